// Round 2
// baseline (287.126 us; speedup 1.0000x reference)
//
#include <hip/hip_runtime.h>
#include <math.h>

// QuantumIntegrator: r_embed [B=4, S=4096, 2] fp32, dt [4] fp32.
// Outputs (flat fp32): r_final [4,4096,2] then score [4,4096,4096].
//
// R4 theory: rocprof top-5 are all ~163us fills => both our kernels <162us,
// so k_pass2 >= 274-162 ~= 112us despite writing ~nothing. The block-per-row
// reduce (LDS reduce + 2 barriers + thread-0 serial + per-block latency chain)
// is the cost, not the 268 MB write (floor ~41us @ 6.6 TB/s, proven by fills).
// Fix: one WAVE per row. In-register __shfl_down butterfly, zero LDS, zero
// __syncthreads. Pass1 fuses the 16KB score-row write (16 x 1KB contiguous
// nontemporal dwordx4 stores per wave). 16384 independent waves = full
// latency hiding.
// R5: compile fix — __builtin_nontemporal_store needs a native clang vector
// type, not HIP_vector_type<float,4>. Use ext_vector_type(4) float.

#define S_LEN 4096
#define ROWS  16384   // B*S with B=4 (fixed by setup_inputs)
#define BLK   256     // 4 independent waves per block
#define EPSF  1e-6f
#define RATE  0.01f
#define MINR  0.1f
#define MAXR  2.0f

typedef float f32x4 __attribute__((ext_vector_type(4)));

// ws layout (floats): [0, 2*ROWS) r_mid; [2*ROWS, 4*ROWS) k1; [4*ROWS, 5*ROWS) sum_score.

__global__ __launch_bounds__(BLK) void k_pass1(
    const float2* __restrict__ r_in,              // fp32 (x,y) per (b,s)
    const float*  __restrict__ dt_in,             // fp32 per batch
    float* __restrict__ ws,
    float* __restrict__ score_out)                // fp32, [ROWS, S_LEN]
{
    const int lane = threadIdx.x & 63;
    const int row  = (blockIdx.x << 2) + (threadIdx.x >> 6);   // wave-per-row
    const int b = row >> 12;
    const int s = row & (S_LEN - 1);
    const float2* rb  = r_in + ((size_t)b << 12);
    const float4* rb4 = (const float4*)rb;        // one float4 = points (2i, 2i+1)
    const float2 rs = rb[s];

    // Triangular reduce: denom + context numerator. Coalesced float4, L1-hot.
    float dsum = 0.f, nx = 0.f, ny = 0.f;
    for (int i = lane; 2*i <= s; i += 64) {
        float4 p = rb4[i];
        float d0 = fmaxf(rs.x * p.x + rs.y * p.y, 0.f);   // t = 2i (<= s by loop cond)
        dsum += d0; nx = fmaf(d0, p.x, nx); ny = fmaf(d0, p.y, ny);
        if (2*i + 1 <= s) {
            float d1 = fmaxf(rs.x * p.z + rs.y * p.w, 0.f);
            dsum += d1; nx = fmaf(d1, p.z, nx); ny = fmaf(d1, p.w, ny);
        }
    }
    // Wave-local butterfly reduce: no LDS, no barrier. Lane 0 holds totals.
    #pragma unroll
    for (int off = 32; off > 0; off >>= 1) {
        dsum += __shfl_down(dsum, off);
        nx   += __shfl_down(nx, off);
        ny   += __shfl_down(ny, off);
    }
    const float D   = __shfl(dsum, 0);            // broadcast total to all lanes
    const float dc  = fmaxf(D, EPSF);
    const float inv = 1.f / dc;

    if (lane == 0) {
        const float dtb = dt_in[b];
        float k1x = dtb * nx / dc;
        float k1y = dtb * ny / dc;
        if (!isfinite(k1x)) k1x = 0.f;
        if (!isfinite(k1y)) k1y = 0.f;
        float rmx = rs.x + k1x, rmy = rs.y + k1y;
        if (!isfinite(rmx)) rmx = rs.x;
        if (!isfinite(rmy)) rmy = rs.y;
        ws[2*row]              = rmx;  ws[2*row + 1]              = rmy;  // r_mid
        ws[2*ROWS + 2*row]     = k1x;  ws[2*ROWS + 2*row + 1]     = k1y;  // k1
        ws[4*ROWS + row]       = D / dc;           // row-sum of normalized score
    }

    // Score row: wave writes its full 16KB row as 16 contiguous 1KB NT stores.
    // relu(dot)*inv == relu(dot*inv) since inv > 0.
    const float isx = rs.x * inv, isy = rs.y * inv;
    float* orow = score_out + (size_t)row * S_LEN;
    #pragma unroll 4
    for (int q = 0; q < 16; q++) {
        const int t0 = (lane << 2) + (q << 8);    // 4*lane + 256*q
        f32x4 v = (f32x4)(0.f);
        if ((q << 8) <= s) {                      // wave-uniform: any lane in range?
            if (t0 <= s) {
                const float4 p01 = rb4[t0 >> 1];        // points t0, t0+1
                const float4 p23 = rb4[(t0 >> 1) + 1];  // points t0+2, t0+3 (t0+3 <= 4095)
                v.x = fmaxf(isx * p01.x + isy * p01.y, 0.f);
                v.y = (t0 + 1 <= s) ? fmaxf(isx * p01.z + isy * p01.w, 0.f) : 0.f;
                v.z = (t0 + 2 <= s) ? fmaxf(isx * p23.x + isy * p23.y, 0.f) : 0.f;
                v.w = (t0 + 3 <= s) ? fmaxf(isx * p23.z + isy * p23.w, 0.f) : 0.f;
            }
        }
        __builtin_nontemporal_store(v, (f32x4*)(orow + t0));
    }
}

__global__ __launch_bounds__(BLK) void k_pass2(
    const float2* __restrict__ r_in,
    const float*  __restrict__ dt_in,
    const float*  __restrict__ ws,
    float* __restrict__ rfinal_out)               // fp32, [ROWS, 2]
{
    const int lane = threadIdx.x & 63;
    const int row  = (blockIdx.x << 2) + (threadIdx.x >> 6);
    const int b = row >> 12;
    const int s = row & (S_LEN - 1);
    const float2* rm  = ((const float2*)ws) + ((size_t)b << 12);   // r_mid for batch
    const float4* rm4 = (const float4*)rm;
    const float2 rs = rm[s];

    float dsum = 0.f, nx = 0.f, ny = 0.f;
    for (int i = lane; 2*i <= s; i += 64) {
        float4 p = rm4[i];
        float d0 = fmaxf(rs.x * p.x + rs.y * p.y, 0.f);
        dsum += d0; nx = fmaf(d0, p.x, nx); ny = fmaf(d0, p.y, ny);
        if (2*i + 1 <= s) {
            float d1 = fmaxf(rs.x * p.z + rs.y * p.w, 0.f);
            dsum += d1; nx = fmaf(d1, p.z, nx); ny = fmaf(d1, p.w, ny);
        }
    }
    #pragma unroll
    for (int off = 32; off > 0; off >>= 1) {
        dsum += __shfl_down(dsum, off);
        nx   += __shfl_down(nx, off);
        ny   += __shfl_down(ny, off);
    }

    if (lane == 0) {
        const float dc  = fmaxf(dsum, EPSF);
        const float dtb = dt_in[b];
        float k2x = dtb * nx / dc;
        float k2y = dtb * ny / dc;
        if (!isfinite(k2x)) k2x = 0.f;
        if (!isfinite(k2y)) k2y = 0.f;
        const float2 r0  = r_in[row];
        const float  k1x = ws[2*ROWS + 2*row], k1y = ws[2*ROWS + 2*row + 1];
        const float rnx = r0.x + 0.5f * (k1x + k2x);
        const float rny = r0.y + 0.5f * (k1y + k2y);
        const float nr  = fmaxf(sqrtf(rnx*rnx + rny*rny), EPSF);
        const float ar  = fminf(fmaxf(nr + ws[4*ROWS + row] * RATE, MINR), MAXR);
        const float sc  = ar / nr;
        float fx = rnx * sc, fy = rny * sc;
        if (!isfinite(fx)) fx = r0.x;
        if (!isfinite(fy)) fy = r0.y;
        rfinal_out[2*row]     = fx;
        rfinal_out[2*row + 1] = fy;
    }
}

extern "C" void kernel_launch(void* const* d_in, const int* in_sizes, int n_in,
                              void* d_out, int out_size, void* d_ws, size_t ws_size,
                              hipStream_t stream) {
    const float2* r_in  = (const float2*)d_in[0];   // fp32 [4,4096,2]
    const float*  dt_in = (const float*)d_in[1];    // fp32 [4]
    float* out = (float*)d_out;
    float* ws  = (float*)d_ws;

    // d_out: first ROWS*2 floats = r_final, then ROWS*S_LEN floats = score.
    float* rfinal_out = out;
    float* score_out  = out + (size_t)2 * ROWS;

    hipLaunchKernelGGL(k_pass1, dim3(ROWS / 4), dim3(BLK), 0, stream,
                       r_in, dt_in, ws, score_out);
    hipLaunchKernelGGL(k_pass2, dim3(ROWS / 4), dim3(BLK), 0, stream,
                       r_in, dt_in, ws, rfinal_out);
}